// Round 1
// baseline (672.612 us; speedup 1.0000x reference)
//
#include <hip/hip_runtime.h>
#include <hip/hip_bf16.h>
#include <math.h>

#define NDIM 384
#define NHEADS 12
#define NTOK 196
#define NBATCH 256
#define M_TOK (NBATCH * NTOK)   // 50176
#define NHID 1536
#define THREE_DIM 1152
#define HD 32
#define EPSV 1e-5f

typedef __hip_bfloat16 bf16;
typedef __attribute__((ext_vector_type(8))) short short8;
typedef __attribute__((ext_vector_type(4))) float f32x4;

__device__ __forceinline__ void gload_lds16(const void* g, void* l) {
  __builtin_amdgcn_global_load_lds((const __attribute__((address_space(1))) void*)g,
                                   (__attribute__((address_space(3))) void*)l, 16, 0, 0);
}

// ---------------- prep: weight transpose fp32 -> bf16 (dst[n*K+k] = src[k*N+n])
__global__ void k_transpose_bf16(const float* __restrict__ src, bf16* __restrict__ dst,
                                 int K, int N) {
  int idx = blockIdx.x * 256 + threadIdx.x;
  if (idx >= K * N) return;
  int k = idx / N, n = idx - k * N;
  dst[n * K + k] = __float2bfloat16(src[idx]);
}

// ---------------- prep: dense rel-pos bias  bias_mat[h][q][k]
__global__ void k_build_bias(const float* __restrict__ table, const int* __restrict__ rpi,
                             float* __restrict__ bias_mat) {
  int idx = blockIdx.x * 256 + threadIdx.x;
  if (idx >= NTOK * NTOK) return;
  int r = rpi[idx];
#pragma unroll
  for (int h = 0; h < NHEADS; ++h)
    bias_mat[h * (NTOK * NTOK) + idx] = table[r * NHEADS + h];
}

// ---------------- LayerNorm: 1 wave per token, 4 tokens per block
__global__ __launch_bounds__(256) void k_layernorm(const float* __restrict__ x,
                                                   const float* __restrict__ w,
                                                   const float* __restrict__ b,
                                                   bf16* __restrict__ out) {
  int token = blockIdx.x * 4 + (threadIdx.x >> 6);
  int lane = threadIdx.x & 63;
  const float* xr = x + (size_t)token * NDIM;
  float v[6];
  float s = 0.f;
#pragma unroll
  for (int i = 0; i < 6; ++i) { v[i] = xr[lane + i * 64]; s += v[i]; }
#pragma unroll
  for (int off = 32; off >= 1; off >>= 1) s += __shfl_xor(s, off);
  float mu = s * (1.f / NDIM);
  float s2 = 0.f;
#pragma unroll
  for (int i = 0; i < 6; ++i) { float d = v[i] - mu; s2 += d * d; }
#pragma unroll
  for (int off = 32; off >= 1; off >>= 1) s2 += __shfl_xor(s2, off);
  float r = rsqrtf(s2 * (1.f / NDIM) + EPSV);
  bf16* orow = out + (size_t)token * NDIM;
#pragma unroll
  for (int i = 0; i < 6; ++i) {
    int c = lane + i * 64;
    orow[c] = __float2bfloat16((v[i] - mu) * r * w[c] + b[c]);
  }
}

// ---------------- GEMM: C[M,N] = A[M,K] * Bt[N,K]^T + bias
// EPI: 0 = bf16 out, 1 = bf16 out + exact GELU, 2 = f32 out + residual
template <int EPI>
__global__ __launch_bounds__(256) void k_gemm_bt(const bf16* __restrict__ A,
                                                 const bf16* __restrict__ Bt,
                                                 const float* __restrict__ bias,
                                                 const float* __restrict__ resid,
                                                 void* __restrict__ Cout,
                                                 int Nn, int K) {
  __shared__ bf16 As[128 * 32];
  __shared__ bf16 Bs[128 * 32];
  const int tid = threadIdx.x;
  const int wave = tid >> 6, lane = tid & 63;
  const int lo = lane & 15, hi = lane >> 4;
  const int wm = wave >> 1, wn = wave & 1;
  const int m0 = blockIdx.y * 128, n0 = blockIdx.x * 128;

  f32x4 acc[4][4];
#pragma unroll
  for (int i = 0; i < 4; ++i) {
#pragma unroll
    for (int j = 0; j < 4; ++j) acc[i][j] = (f32x4){0.f, 0.f, 0.f, 0.f};
  }

  const int nk = K >> 5;
  for (int ks = 0; ks < nk; ++ks) {
    int k0 = ks << 5;
#pragma unroll
    for (int it = 0; it < 2; ++it) {
      int c = it * 256 + tid;  // 0..511
      int row = c >> 2, part = c & 3;
      gload_lds16(A + (size_t)(m0 + row) * K + k0 + part * 8, As + c * 8);
      gload_lds16(Bt + (size_t)(n0 + row) * K + k0 + part * 8, Bs + c * 8);
    }
    __syncthreads();
    short8 af[4], bfr[4];
#pragma unroll
    for (int i = 0; i < 4; ++i) {
      af[i] = *(const short8*)(As + (wm * 64 + i * 16 + lo) * 32 + hi * 8);
      bfr[i] = *(const short8*)(Bs + (wn * 64 + i * 16 + lo) * 32 + hi * 8);
    }
#pragma unroll
    for (int i = 0; i < 4; ++i) {
#pragma unroll
      for (int j = 0; j < 4; ++j)
        acc[i][j] = __builtin_amdgcn_mfma_f32_16x16x32_bf16(af[i], bfr[j], acc[i][j], 0, 0, 0);
    }
    __syncthreads();
  }

#pragma unroll
  for (int i = 0; i < 4; ++i) {
    int r = m0 + wm * 64 + i * 16 + hi * 4;
#pragma unroll
    for (int j = 0; j < 4; ++j) {
      int cb = n0 + wn * 64 + j * 16 + lo;
      float bv = bias[cb];
#pragma unroll
      for (int e = 0; e < 4; ++e) {
        size_t idx = (size_t)(r + e) * Nn + cb;
        float val = acc[i][j][e] + bv;
        if (EPI == 1) val = 0.5f * val * (1.f + erff(val * 0.70710678118f));
        if (EPI == 2) {
          ((float*)Cout)[idx] = resid[idx] + val;
        } else {
          ((bf16*)Cout)[idx] = __float2bfloat16(val);
        }
      }
    }
  }
}

// ---------------- attention: 1 wave per (16-q-row tile, head, batch)
__global__ __launch_bounds__(64) void k_attn(const bf16* __restrict__ qkv,
                                             const float* __restrict__ bias_mat,
                                             bf16* __restrict__ out) {
  __shared__ bf16 P[16][224];
  const int lane = threadIdx.x;
  const int lo = lane & 15, hi = lane >> 4;
  const int qt = blockIdx.x;  // 0..12
  const int h = blockIdx.y;   // 0..11
  const int b = blockIdx.z;   // 0..255
  const float scale = 0.17677669529663687f;

  // zero pad columns 208..223
#pragma unroll
  for (int i = 0; i < 4; ++i) {
    int idx = lane + i * 64;
    P[idx >> 4][208 + (idx & 15)] = __float2bfloat16(0.f);
  }

  // Q fragment (A operand): row = lo, dim chunk = hi*8
  int qrow = qt * 16 + lo;
  short8 qf = {0, 0, 0, 0, 0, 0, 0, 0};
  if (qrow < NTOK)
    qf = *(const short8*)(qkv + (size_t)(b * NTOK + qrow) * THREE_DIM + h * HD + hi * 8);

  // S = Q K^T  (13 key tiles of 16)
  f32x4 s[13];
#pragma unroll
  for (int kt = 0; kt < 13; ++kt) {
    int key = kt * 16 + lo;
    short8 kf = {0, 0, 0, 0, 0, 0, 0, 0};
    if (key < NTOK)
      kf = *(const short8*)(qkv + (size_t)(b * NTOK + key) * THREE_DIM + NDIM + h * HD + hi * 8);
    f32x4 z = {0.f, 0.f, 0.f, 0.f};
    s[kt] = __builtin_amdgcn_mfma_f32_16x16x32_bf16(qf, kf, z, 0, 0, 0);
  }

  // bias + mask + softmax; row e lives in lanes sharing hi, cols spread over lo
  float p[13][4];
#pragma unroll
  for (int e = 0; e < 4; ++e) {
    int qg = qt * 16 + hi * 4 + e;
    int qc = qg < NTOK ? qg : NTOK - 1;
    const float* brow = bias_mat + ((size_t)h * NTOK + qc) * NTOK;
    float mx = -1e30f;
#pragma unroll
    for (int kt = 0; kt < 13; ++kt) {
      int key = kt * 16 + lo;
      float v = (key < NTOK) ? (s[kt][e] * scale + brow[key]) : -1e30f;
      p[kt][e] = v;
      mx = fmaxf(mx, v);
    }
#pragma unroll
    for (int off = 8; off >= 1; off >>= 1) mx = fmaxf(mx, __shfl_xor(mx, off));
    float sm = 0.f;
#pragma unroll
    for (int kt = 0; kt < 13; ++kt) {
      float pe = __expf(p[kt][e] - mx);
      p[kt][e] = pe;
      sm += pe;
    }
#pragma unroll
    for (int off = 8; off >= 1; off >>= 1) sm += __shfl_xor(sm, off);
    float inv = 1.f / sm;
#pragma unroll
    for (int kt = 0; kt < 13; ++kt) p[kt][e] *= inv;
  }

  // P -> LDS (D layout -> A layout relayout)
#pragma unroll
  for (int kt = 0; kt < 13; ++kt) {
#pragma unroll
    for (int e = 0; e < 4; ++e) P[hi * 4 + e][kt * 16 + lo] = __float2bfloat16(p[kt][e]);
  }
  __syncthreads();

  // O = P V   (7 chunks of 32 keys; 2 n-tiles for 32 dims)
  f32x4 o[2] = {{0.f, 0.f, 0.f, 0.f}, {0.f, 0.f, 0.f, 0.f}};
#pragma unroll
  for (int c = 0; c < 7; ++c) {
    short8 pa = *(const short8*)(&P[lo][c * 32 + hi * 8]);
#pragma unroll
    for (int n = 0; n < 2; ++n) {
      union { short8 v; bf16 x[8]; } vf;
#pragma unroll
      for (int j = 0; j < 8; ++j) {
        int key = c * 32 + hi * 8 + j;
        int kc = key < NTOK ? key : NTOK - 1;
        vf.x[j] = qkv[(size_t)(b * NTOK + kc) * THREE_DIM + 2 * NDIM + h * HD + n * 16 + lo];
      }
      o[n] = __builtin_amdgcn_mfma_f32_16x16x32_bf16(pa, vf.v, o[n], 0, 0, 0);
    }
  }

  // store O (bf16, token-major)
#pragma unroll
  for (int n = 0; n < 2; ++n) {
#pragma unroll
    for (int e = 0; e < 4; ++e) {
      int qg = qt * 16 + hi * 4 + e;
      if (qg < NTOK)
        out[(size_t)(b * NTOK + qg) * NDIM + h * HD + n * 16 + lo] = __float2bfloat16(o[n][e]);
    }
  }
}

extern "C" void kernel_launch(void* const* d_in, const int* in_sizes, int n_in,
                              void* d_out, int out_size, void* d_ws, size_t ws_size,
                              hipStream_t stream) {
  const float* x       = (const float*)d_in[0];
  const float* norm1_w = (const float*)d_in[1];
  const float* norm1_b = (const float*)d_in[2];
  const float* qkv_w   = (const float*)d_in[3];
  const float* qkv_b   = (const float*)d_in[4];
  const float* proj_w  = (const float*)d_in[5];
  const float* proj_b  = (const float*)d_in[6];
  const float* rpb     = (const float*)d_in[7];
  const float* norm2_w = (const float*)d_in[8];
  const float* norm2_b = (const float*)d_in[9];
  const float* fc1_w   = (const float*)d_in[10];
  const float* fc1_b   = (const float*)d_in[11];
  const float* fc2_w   = (const float*)d_in[12];
  const float* fc2_b   = (const float*)d_in[13];
  const int*   rpi     = (const int*)d_in[14];
  float* out = (float*)d_out;

  char* ws = (char*)d_ws;
  // region 0 (154,140,672 B): qkv bf16 (115.6MB), later mlp1 bf16 (154.1MB)
  bf16* qkv_buf = (bf16*)ws;
  bf16* mlp1 = (bf16*)ws;
  // region 1 (38,535,168 B): h1 -> attn_out -> h2
  bf16* hbuf = (bf16*)(ws + 154140672);
  // weights (bf16, transposed)
  bf16* wqkv_t = (bf16*)(ws + 154140672 + 38535168);
  bf16* wproj_t = wqkv_t + 442368;
  bf16* wfc1_t = wproj_t + 147456;
  bf16* wfc2_t = wfc1_t + 589824;
  float* bias_mat = (float*)(wfc2_t + 589824);  // 12*196*196 f32

  k_transpose_bf16<<<(442368 + 255) / 256, 256, 0, stream>>>(qkv_w, wqkv_t, 384, 1152);
  k_transpose_bf16<<<(147456 + 255) / 256, 256, 0, stream>>>(proj_w, wproj_t, 384, 384);
  k_transpose_bf16<<<(589824 + 255) / 256, 256, 0, stream>>>(fc1_w, wfc1_t, 384, 1536);
  k_transpose_bf16<<<(589824 + 255) / 256, 256, 0, stream>>>(fc2_w, wfc2_t, 1536, 384);
  k_build_bias<<<(NTOK * NTOK + 255) / 256, 256, 0, stream>>>(rpb, rpi, bias_mat);

  // h1 = LN1(x)
  k_layernorm<<<M_TOK / 4, 256, 0, stream>>>(x, norm1_w, norm1_b, hbuf);
  // qkv = h1 @ qkv_w + qkv_b
  k_gemm_bt<0><<<dim3(9, 392), 256, 0, stream>>>(hbuf, wqkv_t, qkv_b, nullptr, qkv_buf, 1152, 384);
  // attn_out = softmax(q k^T * scale + bias) v   (overwrites h1 region)
  k_attn<<<dim3(13, 12, 256), 64, 0, stream>>>(qkv_buf, bias_mat, hbuf);
  // x2 = x + attn_out @ proj_w + proj_b   (f32, into d_out)
  k_gemm_bt<2><<<dim3(3, 392), 256, 0, stream>>>(hbuf, wproj_t, proj_b, x, out, 384, 384);
  // h2 = LN2(x2)
  k_layernorm<<<M_TOK / 4, 256, 0, stream>>>(out, norm2_w, norm2_b, hbuf);
  // mlp1 = gelu(h2 @ fc1_w + fc1_b)
  k_gemm_bt<1><<<dim3(12, 392), 256, 0, stream>>>(hbuf, wfc1_t, fc1_b, nullptr, mlp1, 1536, 384);
  // out = x2 + mlp1 @ fc2_w + fc2_b
  k_gemm_bt<2><<<dim3(3, 392), 256, 0, stream>>>(mlp1, wfc2_t, fc2_b, out, out, 384, 1536);
}

// Round 2
// 603.916 us; speedup vs baseline: 1.1138x; 1.1138x over previous
//
#include <hip/hip_runtime.h>
#include <hip/hip_bf16.h>
#include <math.h>

#define NDIM 384
#define NHEADS 12
#define NTOK 196
#define NBATCH 256
#define M_TOK (NBATCH * NTOK)   // 50176
#define NHID 1536
#define THREE_DIM 1152
#define HD 32
#define EPSV 1e-5f

typedef __hip_bfloat16 bf16;
typedef __attribute__((ext_vector_type(8))) short short8;
typedef __attribute__((ext_vector_type(4))) float f32x4;

__device__ __forceinline__ void gload_lds16(const void* g, void* l) {
  __builtin_amdgcn_global_load_lds((const __attribute__((address_space(1))) void*)g,
                                   (__attribute__((address_space(3))) void*)l, 16, 0, 0);
}

// ---------------- prep: weight transpose fp32 -> bf16 (dst[n*K+k] = src[k*N+n])
__global__ void k_transpose_bf16(const float* __restrict__ src, bf16* __restrict__ dst,
                                 int K, int N) {
  int idx = blockIdx.x * 256 + threadIdx.x;
  if (idx >= K * N) return;
  int k = idx / N, n = idx - k * N;
  dst[n * K + k] = __float2bfloat16(src[idx]);
}

// ---------------- prep: dense rel-pos bias  bias_mat[h][q][k]
__global__ void k_build_bias(const float* __restrict__ table, const int* __restrict__ rpi,
                             float* __restrict__ bias_mat) {
  int idx = blockIdx.x * 256 + threadIdx.x;
  if (idx >= NTOK * NTOK) return;
  int r = rpi[idx];
#pragma unroll
  for (int h = 0; h < NHEADS; ++h)
    bias_mat[h * (NTOK * NTOK) + idx] = table[r * NHEADS + h];
}

// ---------------- LayerNorm: 1 wave per token, 4 tokens per block
__global__ __launch_bounds__(256) void k_layernorm(const float* __restrict__ x,
                                                   const float* __restrict__ w,
                                                   const float* __restrict__ b,
                                                   bf16* __restrict__ out) {
  int token = blockIdx.x * 4 + (threadIdx.x >> 6);
  int lane = threadIdx.x & 63;
  const float* xr = x + (size_t)token * NDIM;
  float v[6];
  float s = 0.f;
#pragma unroll
  for (int i = 0; i < 6; ++i) { v[i] = xr[lane + i * 64]; s += v[i]; }
#pragma unroll
  for (int off = 32; off >= 1; off >>= 1) s += __shfl_xor(s, off);
  float mu = s * (1.f / NDIM);
  float s2 = 0.f;
#pragma unroll
  for (int i = 0; i < 6; ++i) { float d = v[i] - mu; s2 += d * d; }
#pragma unroll
  for (int off = 32; off >= 1; off >>= 1) s2 += __shfl_xor(s2, off);
  float r = rsqrtf(s2 * (1.f / NDIM) + EPSV);
  bf16* orow = out + (size_t)token * NDIM;
#pragma unroll
  for (int i = 0; i < 6; ++i) {
    int c = lane + i * 64;
    orow[c] = __float2bfloat16((v[i] - mu) * r * w[c] + b[c]);
  }
}

// ---------------- GEMM: C[M,N] = A[M,K] * Bt[N,K]^T + bias
// EPI: 0 = bf16 out, 1 = bf16 out + exact GELU, 2 = f32 out + residual
template <int EPI>
__global__ __launch_bounds__(256) void k_gemm_bt(const bf16* __restrict__ A,
                                                 const bf16* __restrict__ Bt,
                                                 const float* __restrict__ bias,
                                                 const float* __restrict__ resid,
                                                 void* __restrict__ Cout,
                                                 int Nn, int K) {
  __shared__ bf16 As[128 * 32];
  __shared__ bf16 Bs[128 * 32];
  const int tid = threadIdx.x;
  const int wave = tid >> 6, lane = tid & 63;
  const int lo = lane & 15, hi = lane >> 4;
  const int wm = wave >> 1, wn = wave & 1;
  const int m0 = blockIdx.y * 128, n0 = blockIdx.x * 128;

  f32x4 acc[4][4];
#pragma unroll
  for (int i = 0; i < 4; ++i) {
#pragma unroll
    for (int j = 0; j < 4; ++j) acc[i][j] = (f32x4){0.f, 0.f, 0.f, 0.f};
  }

  const int nk = K >> 5;
  for (int ks = 0; ks < nk; ++ks) {
    int k0 = ks << 5;
#pragma unroll
    for (int it = 0; it < 2; ++it) {
      int c = it * 256 + tid;  // 0..511
      int row = c >> 2, part = c & 3;
      gload_lds16(A + (size_t)(m0 + row) * K + k0 + part * 8, As + c * 8);
      gload_lds16(Bt + (size_t)(n0 + row) * K + k0 + part * 8, Bs + c * 8);
    }
    __syncthreads();
    short8 af[4], bfr[4];
#pragma unroll
    for (int i = 0; i < 4; ++i) {
      af[i] = *(const short8*)(As + (wm * 64 + i * 16 + lo) * 32 + hi * 8);
      bfr[i] = *(const short8*)(Bs + (wn * 64 + i * 16 + lo) * 32 + hi * 8);
    }
#pragma unroll
    for (int i = 0; i < 4; ++i) {
#pragma unroll
      for (int j = 0; j < 4; ++j)
        acc[i][j] = __builtin_amdgcn_mfma_f32_16x16x32_bf16(af[i], bfr[j], acc[i][j], 0, 0, 0);
    }
    __syncthreads();
  }

#pragma unroll
  for (int i = 0; i < 4; ++i) {
    int r = m0 + wm * 64 + i * 16 + hi * 4;
#pragma unroll
    for (int j = 0; j < 4; ++j) {
      int cb = n0 + wn * 64 + j * 16 + lo;
      float bv = bias[cb];
#pragma unroll
      for (int e = 0; e < 4; ++e) {
        size_t idx = (size_t)(r + e) * Nn + cb;
        float val = acc[i][j][e] + bv;
        if (EPI == 1) val = 0.5f * val * (1.f + erff(val * 0.70710678118f));
        if (EPI == 2) {
          ((float*)Cout)[idx] = resid[idx] + val;
        } else {
          ((bf16*)Cout)[idx] = __float2bfloat16(val);
        }
      }
    }
  }
}

// ---------------- attention: 1 block (4 waves) per (head, batch)
// LDS: V transposed (Vt[d][key], padded stride 232) staged once;
//      per-wave P tile (16 x 232). No in-loop barriers.
__global__ __launch_bounds__(256) void k_attn(const bf16* __restrict__ qkv,
                                              const float* __restrict__ bias_mat,
                                              bf16* __restrict__ out) {
  __shared__ __align__(16) bf16 Vt[32][232];
  __shared__ __align__(16) bf16 Ps[4][16][232];
  const int tid = threadIdx.x;
  const int wave = tid >> 6, lane = tid & 63;
  const int lo = lane & 15, hi = lane >> 4;
  const int h = blockIdx.x;   // 0..11
  const int b = blockIdx.y;   // 0..255
  const float scale = 0.17677669529663687f;
  const bf16* Kbase = qkv + (size_t)b * NTOK * THREE_DIM + NDIM + h * HD;
  const bf16* Vbase = qkv + (size_t)b * NTOK * THREE_DIM + 2 * NDIM + h * HD;
  const bf16* Qbase = qkv + (size_t)b * NTOK * THREE_DIM + h * HD;

  // ---- stage V transposed: Vt[d][t] = V[t][d]
  union U8 { short8 v; bf16 x[8]; };
  for (int u = tid; u < NTOK * 4; u += 256) {
    int t = u >> 2, dseg = (u & 3) * 8;
    U8 vv;
    vv.v = *(const short8*)(Vbase + (size_t)t * THREE_DIM + dseg);
#pragma unroll
    for (int j = 0; j < 8; ++j) Vt[dseg + j][t] = vv.x[j];
  }
  // zero pad keys 196..223
  for (int u = tid; u < 32 * 28; u += 256) {
    int d = u / 28, c = 196 + u % 28;
    Vt[d][c] = __float2bfloat16(0.f);
  }
  // zero P pad cols 208..223 (per wave)
  for (int i = lane; i < 16 * 16; i += 64) {
    Ps[wave][i >> 4][208 + (i & 15)] = __float2bfloat16(0.f);
  }
  __syncthreads();

  // ---- each wave handles q-tiles wave, wave+4, wave+8 (and 12 for wave 0)
  for (int qt = wave; qt < 13; qt += 4) {
    int qrow = qt * 16 + lo;
    short8 qf = {0, 0, 0, 0, 0, 0, 0, 0};
    if (qrow < NTOK) qf = *(const short8*)(Qbase + (size_t)qrow * THREE_DIM + hi * 8);

    // S = Q K^T (13 key tiles of 16); K fragments straight from global (L2-hot)
    f32x4 s[13];
#pragma unroll
    for (int kt = 0; kt < 13; ++kt) {
      int key = kt * 16 + lo;
      short8 kf = {0, 0, 0, 0, 0, 0, 0, 0};
      if (key < NTOK) kf = *(const short8*)(Kbase + (size_t)key * THREE_DIM + hi * 8);
      f32x4 z = {0.f, 0.f, 0.f, 0.f};
      s[kt] = __builtin_amdgcn_mfma_f32_16x16x32_bf16(qf, kf, z, 0, 0, 0);
    }

    // bias + mask + softmax (in place in s); row e lives in 16-lane group (hi)
#pragma unroll
    for (int e = 0; e < 4; ++e) {
      int qg = qt * 16 + hi * 4 + e;
      int qc = qg < NTOK ? qg : NTOK - 1;
      const float* brow = bias_mat + ((size_t)h * NTOK + qc) * NTOK;
      float mx = -1e30f;
#pragma unroll
      for (int kt = 0; kt < 13; ++kt) {
        int key = kt * 16 + lo;
        float v = (key < NTOK) ? (s[kt][e] * scale + brow[key]) : -1e30f;
        s[kt][e] = v;
        mx = fmaxf(mx, v);
      }
#pragma unroll
      for (int off = 8; off >= 1; off >>= 1) mx = fmaxf(mx, __shfl_xor(mx, off));
      float sm = 0.f;
#pragma unroll
      for (int kt = 0; kt < 13; ++kt) {
        float pe = __expf(s[kt][e] - mx);
        s[kt][e] = pe;
        sm += pe;
      }
#pragma unroll
      for (int off = 8; off >= 1; off >>= 1) sm += __shfl_xor(sm, off);
      float inv = 1.f / sm;
#pragma unroll
      for (int kt = 0; kt < 13; ++kt) s[kt][e] *= inv;
    }

    // P -> LDS (D layout -> A layout relayout), per-wave region, no barrier
#pragma unroll
    for (int kt = 0; kt < 13; ++kt) {
#pragma unroll
      for (int e = 0; e < 4; ++e)
        Ps[wave][hi * 4 + e][kt * 16 + lo] = __float2bfloat16(s[kt][e]);
    }

    // O = P V   (7 chunks of 32 keys; 2 n-tiles for 32 dims)
    f32x4 o[2] = {{0.f, 0.f, 0.f, 0.f}, {0.f, 0.f, 0.f, 0.f}};
#pragma unroll
    for (int c = 0; c < 7; ++c) {
      short8 pa = *(const short8*)(&Ps[wave][lo][c * 32 + hi * 8]);
#pragma unroll
      for (int n = 0; n < 2; ++n) {
        short8 vf = *(const short8*)(&Vt[n * 16 + lo][c * 32 + hi * 8]);
        o[n] = __builtin_amdgcn_mfma_f32_16x16x32_bf16(pa, vf, o[n], 0, 0, 0);
      }
    }

    // store O (bf16, token-major)
#pragma unroll
    for (int n = 0; n < 2; ++n) {
#pragma unroll
      for (int e = 0; e < 4; ++e) {
        int qg = qt * 16 + hi * 4 + e;
        if (qg < NTOK)
          out[(size_t)(b * NTOK + qg) * NDIM + h * HD + n * 16 + lo] = __float2bfloat16(o[n][e]);
      }
    }
  }
}

extern "C" void kernel_launch(void* const* d_in, const int* in_sizes, int n_in,
                              void* d_out, int out_size, void* d_ws, size_t ws_size,
                              hipStream_t stream) {
  const float* x       = (const float*)d_in[0];
  const float* norm1_w = (const float*)d_in[1];
  const float* norm1_b = (const float*)d_in[2];
  const float* qkv_w   = (const float*)d_in[3];
  const float* qkv_b   = (const float*)d_in[4];
  const float* proj_w  = (const float*)d_in[5];
  const float* proj_b  = (const float*)d_in[6];
  const float* rpb     = (const float*)d_in[7];
  const float* norm2_w = (const float*)d_in[8];
  const float* norm2_b = (const float*)d_in[9];
  const float* fc1_w   = (const float*)d_in[10];
  const float* fc1_b   = (const float*)d_in[11];
  const float* fc2_w   = (const float*)d_in[12];
  const float* fc2_b   = (const float*)d_in[13];
  const int*   rpi     = (const int*)d_in[14];
  float* out = (float*)d_out;

  char* ws = (char*)d_ws;
  // region 0 (154,140,672 B): qkv bf16 (115.6MB), later mlp1 bf16 (154.1MB)
  bf16* qkv_buf = (bf16*)ws;
  bf16* mlp1 = (bf16*)ws;
  // region 1 (38,535,168 B): h1 -> attn_out -> h2
  bf16* hbuf = (bf16*)(ws + 154140672);
  // weights (bf16, transposed)
  bf16* wqkv_t = (bf16*)(ws + 154140672 + 38535168);
  bf16* wproj_t = wqkv_t + 442368;
  bf16* wfc1_t = wproj_t + 147456;
  bf16* wfc2_t = wfc1_t + 589824;
  float* bias_mat = (float*)(wfc2_t + 589824);  // 12*196*196 f32

  k_transpose_bf16<<<(442368 + 255) / 256, 256, 0, stream>>>(qkv_w, wqkv_t, 384, 1152);
  k_transpose_bf16<<<(147456 + 255) / 256, 256, 0, stream>>>(proj_w, wproj_t, 384, 384);
  k_transpose_bf16<<<(589824 + 255) / 256, 256, 0, stream>>>(fc1_w, wfc1_t, 384, 1536);
  k_transpose_bf16<<<(589824 + 255) / 256, 256, 0, stream>>>(fc2_w, wfc2_t, 1536, 384);
  k_build_bias<<<(NTOK * NTOK + 255) / 256, 256, 0, stream>>>(rpb, rpi, bias_mat);

  // h1 = LN1(x)
  k_layernorm<<<M_TOK / 4, 256, 0, stream>>>(x, norm1_w, norm1_b, hbuf);
  // qkv = h1 @ qkv_w + qkv_b
  k_gemm_bt<0><<<dim3(9, 392), 256, 0, stream>>>(hbuf, wqkv_t, qkv_b, nullptr, qkv_buf, 1152, 384);
  // attn_out = softmax(q k^T * scale + bias) v   (overwrites h1 region)
  k_attn<<<dim3(NHEADS, NBATCH), 256, 0, stream>>>(qkv_buf, bias_mat, hbuf);
  // x2 = x + attn_out @ proj_w + proj_b   (f32, into d_out)
  k_gemm_bt<2><<<dim3(3, 392), 256, 0, stream>>>(hbuf, wproj_t, proj_b, x, out, 384, 384);
  // h2 = LN2(x2)
  k_layernorm<<<M_TOK / 4, 256, 0, stream>>>(out, norm2_w, norm2_b, hbuf);
  // mlp1 = gelu(h2 @ fc1_w + fc1_b)
  k_gemm_bt<1><<<dim3(12, 392), 256, 0, stream>>>(hbuf, wfc1_t, fc1_b, nullptr, mlp1, 1536, 384);
  // out = x2 + mlp1 @ fc2_w + fc2_b
  k_gemm_bt<2><<<dim3(3, 392), 256, 0, stream>>>(mlp1, wfc2_t, fc2_b, out, out, 384, 1536);
}

// Round 3
// 544.218 us; speedup vs baseline: 1.2359x; 1.1097x over previous
//
#include <hip/hip_runtime.h>
#include <hip/hip_bf16.h>
#include <math.h>

#define NDIM 384
#define NHEADS 12
#define NTOK 196
#define NBATCH 256
#define M_TOK (NBATCH * NTOK)   // 50176
#define NHID 1536
#define THREE_DIM 1152
#define HD 32
#define EPSV 1e-5f

typedef __hip_bfloat16 bf16;
typedef __attribute__((ext_vector_type(8))) short short8;
typedef __attribute__((ext_vector_type(4))) float f32x4;

__device__ __forceinline__ void gload_lds16(const void* g, void* l) {
  __builtin_amdgcn_global_load_lds((const __attribute__((address_space(1))) void*)g,
                                   (__attribute__((address_space(3))) void*)l, 16, 0, 0);
}

// ---------------- prep: weight transpose fp32 -> bf16 (dst[n*K+k] = src[k*N+n])
__global__ void k_transpose_bf16(const float* __restrict__ src, bf16* __restrict__ dst,
                                 int K, int N) {
  int idx = blockIdx.x * 256 + threadIdx.x;
  if (idx >= K * N) return;
  int k = idx / N, n = idx - k * N;
  dst[n * K + k] = __float2bfloat16(src[idx]);
}

// ---------------- prep: dense rel-pos bias  bias_mat[h][q][k]
__global__ void k_build_bias(const float* __restrict__ table, const int* __restrict__ rpi,
                             float* __restrict__ bias_mat) {
  int idx = blockIdx.x * 256 + threadIdx.x;
  if (idx >= NTOK * NTOK) return;
  int r = rpi[idx];
#pragma unroll
  for (int h = 0; h < NHEADS; ++h)
    bias_mat[h * (NTOK * NTOK) + idx] = table[r * NHEADS + h];
}

// ---------------- LayerNorm: 1 wave per token, 4 tokens per block
__global__ __launch_bounds__(256) void k_layernorm(const float* __restrict__ x,
                                                   const float* __restrict__ w,
                                                   const float* __restrict__ b,
                                                   bf16* __restrict__ out) {
  int token = blockIdx.x * 4 + (threadIdx.x >> 6);
  int lane = threadIdx.x & 63;
  const float* xr = x + (size_t)token * NDIM;
  float v[6];
  float s = 0.f;
#pragma unroll
  for (int i = 0; i < 6; ++i) { v[i] = xr[lane + i * 64]; s += v[i]; }
#pragma unroll
  for (int off = 32; off >= 1; off >>= 1) s += __shfl_xor(s, off);
  float mu = s * (1.f / NDIM);
  float s2 = 0.f;
#pragma unroll
  for (int i = 0; i < 6; ++i) { float d = v[i] - mu; s2 += d * d; }
#pragma unroll
  for (int off = 32; off >= 1; off >>= 1) s2 += __shfl_xor(s2, off);
  float r = rsqrtf(s2 * (1.f / NDIM) + EPSV);
  bf16* orow = out + (size_t)token * NDIM;
#pragma unroll
  for (int i = 0; i < 6; ++i) {
    int c = lane + i * 64;
    orow[c] = __float2bfloat16((v[i] - mu) * r * w[c] + b[c]);
  }
}

// ---------------- GEMM: C[M,N] = A[M,K] * Bt[N,K]^T + bias
// 2-phase double-buffered pipeline + XCD-chunked block swizzle.
// EPI: 0 = bf16 out, 1 = bf16 out + exact GELU, 2 = f32 out + residual
template <int EPI>
__global__ __launch_bounds__(256) void k_gemm_bt(const bf16* __restrict__ A,
                                                 const bf16* __restrict__ Bt,
                                                 const float* __restrict__ bias,
                                                 const float* __restrict__ resid,
                                                 void* __restrict__ Cout,
                                                 int Nn, int K, int nbx) {
  __shared__ bf16 As[2][128 * 32];
  __shared__ bf16 Bs[2][128 * 32];
  const int tid = threadIdx.x;
  const int wave = tid >> 6, lane = tid & 63;
  const int lo = lane & 15, hi = lane >> 4;
  const int wm = wave >> 1, wn = wave & 1;

  // XCD-chunked swizzle (all grids are multiples of 8): consecutive tiles
  // (sharing an A row-panel) land on the same XCD's L2.
  const int nwg = gridDim.x;
  const int swz = (blockIdx.x & 7) * (nwg >> 3) + (blockIdx.x >> 3);
  const int m0 = (swz / nbx) * 128, n0 = (swz % nbx) * 128;

  f32x4 acc[4][4];
#pragma unroll
  for (int i = 0; i < 4; ++i) {
#pragma unroll
    for (int j = 0; j < 4; ++j) acc[i][j] = (f32x4){0.f, 0.f, 0.f, 0.f};
  }

  const int row = tid >> 2, part = tid & 3;          // staging coords (it=0)
  const int row1 = (256 + tid) >> 2, part1 = tid & 3; // it=1 (c=256+tid)

  // prologue: stage K-tile 0 into buffer 0
  gload_lds16(A + (size_t)(m0 + row) * K + part * 8, As[0] + tid * 8);
  gload_lds16(Bt + (size_t)(n0 + row) * K + part * 8, Bs[0] + tid * 8);
  gload_lds16(A + (size_t)(m0 + row1) * K + part1 * 8, As[0] + (256 + tid) * 8);
  gload_lds16(Bt + (size_t)(n0 + row1) * K + part1 * 8, Bs[0] + (256 + tid) * 8);
  __syncthreads();

  const int nk = K >> 5;
  int cur = 0;
  for (int ks = 0; ks < nk; ++ks) {
    // issue next tile's staging first (overlaps with compute below)
    if (ks + 1 < nk) {
      int k0 = (ks + 1) << 5;
      gload_lds16(A + (size_t)(m0 + row) * K + k0 + part * 8, As[cur ^ 1] + tid * 8);
      gload_lds16(Bt + (size_t)(n0 + row) * K + k0 + part * 8, Bs[cur ^ 1] + tid * 8);
      gload_lds16(A + (size_t)(m0 + row1) * K + k0 + part1 * 8, As[cur ^ 1] + (256 + tid) * 8);
      gload_lds16(Bt + (size_t)(n0 + row1) * K + k0 + part1 * 8, Bs[cur ^ 1] + (256 + tid) * 8);
    }
    short8 af[4], bfr[4];
#pragma unroll
    for (int i = 0; i < 4; ++i) {
      af[i] = *(const short8*)(As[cur] + (wm * 64 + i * 16 + lo) * 32 + hi * 8);
      bfr[i] = *(const short8*)(Bs[cur] + (wn * 64 + i * 16 + lo) * 32 + hi * 8);
    }
#pragma unroll
    for (int i = 0; i < 4; ++i) {
#pragma unroll
      for (int j = 0; j < 4; ++j)
        acc[i][j] = __builtin_amdgcn_mfma_f32_16x16x32_bf16(af[i], bfr[j], acc[i][j], 0, 0, 0);
    }
    __syncthreads();  // drains vmcnt (next tile landed) + lgkm; swap buffers
    cur ^= 1;
  }

#pragma unroll
  for (int i = 0; i < 4; ++i) {
    int r = m0 + wm * 64 + i * 16 + hi * 4;
#pragma unroll
    for (int j = 0; j < 4; ++j) {
      int cb = n0 + wn * 64 + j * 16 + lo;
      float bv = bias[cb];
#pragma unroll
      for (int e = 0; e < 4; ++e) {
        size_t idx = (size_t)(r + e) * Nn + cb;
        float val = acc[i][j][e] + bv;
        if (EPI == 1) val = 0.5f * val * (1.f + erff(val * 0.70710678118f));
        if (EPI == 2) {
          ((float*)Cout)[idx] = resid[idx] + val;
        } else {
          ((bf16*)Cout)[idx] = __float2bfloat16(val);
        }
      }
    }
  }
}

// ---------------- attention: 1 block (4 waves) per (head, batch)
__global__ __launch_bounds__(256) void k_attn(const bf16* __restrict__ qkv,
                                              const float* __restrict__ bias_mat,
                                              bf16* __restrict__ out) {
  __shared__ __align__(16) bf16 Vt[32][232];
  __shared__ __align__(16) bf16 Ps[4][16][232];
  const int tid = threadIdx.x;
  const int wave = tid >> 6, lane = tid & 63;
  const int lo = lane & 15, hi = lane >> 4;
  const int h = blockIdx.x;   // 0..11
  const int b = blockIdx.y;   // 0..255
  const float scale = 0.17677669529663687f;
  const bf16* Kbase = qkv + (size_t)b * NTOK * THREE_DIM + NDIM + h * HD;
  const bf16* Vbase = qkv + (size_t)b * NTOK * THREE_DIM + 2 * NDIM + h * HD;
  const bf16* Qbase = qkv + (size_t)b * NTOK * THREE_DIM + h * HD;

  union U8 { short8 v; bf16 x[8]; };
  for (int u = tid; u < NTOK * 4; u += 256) {
    int t = u >> 2, dseg = (u & 3) * 8;
    U8 vv;
    vv.v = *(const short8*)(Vbase + (size_t)t * THREE_DIM + dseg);
#pragma unroll
    for (int j = 0; j < 8; ++j) Vt[dseg + j][t] = vv.x[j];
  }
  for (int u = tid; u < 32 * 28; u += 256) {
    int d = u / 28, c = 196 + u % 28;
    Vt[d][c] = __float2bfloat16(0.f);
  }
  for (int i = lane; i < 16 * 16; i += 64) {
    Ps[wave][i >> 4][208 + (i & 15)] = __float2bfloat16(0.f);
  }
  __syncthreads();

  for (int qt = wave; qt < 13; qt += 4) {
    int qrow = qt * 16 + lo;
    short8 qf = {0, 0, 0, 0, 0, 0, 0, 0};
    if (qrow < NTOK) qf = *(const short8*)(Qbase + (size_t)qrow * THREE_DIM + hi * 8);

    f32x4 s[13];
#pragma unroll
    for (int kt = 0; kt < 13; ++kt) {
      int key = kt * 16 + lo;
      short8 kf = {0, 0, 0, 0, 0, 0, 0, 0};
      if (key < NTOK) kf = *(const short8*)(Kbase + (size_t)key * THREE_DIM + hi * 8);
      f32x4 z = {0.f, 0.f, 0.f, 0.f};
      s[kt] = __builtin_amdgcn_mfma_f32_16x16x32_bf16(qf, kf, z, 0, 0, 0);
    }

#pragma unroll
    for (int e = 0; e < 4; ++e) {
      int qg = qt * 16 + hi * 4 + e;
      int qc = qg < NTOK ? qg : NTOK - 1;
      const float* brow = bias_mat + ((size_t)h * NTOK + qc) * NTOK;
      float mx = -1e30f;
#pragma unroll
      for (int kt = 0; kt < 13; ++kt) {
        int key = kt * 16 + lo;
        float v = (key < NTOK) ? (s[kt][e] * scale + brow[key]) : -1e30f;
        s[kt][e] = v;
        mx = fmaxf(mx, v);
      }
#pragma unroll
      for (int off = 8; off >= 1; off >>= 1) mx = fmaxf(mx, __shfl_xor(mx, off));
      float sm = 0.f;
#pragma unroll
      for (int kt = 0; kt < 13; ++kt) {
        float pe = __expf(s[kt][e] - mx);
        s[kt][e] = pe;
        sm += pe;
      }
#pragma unroll
      for (int off = 8; off >= 1; off >>= 1) sm += __shfl_xor(sm, off);
      float inv = 1.f / sm;
#pragma unroll
      for (int kt = 0; kt < 13; ++kt) s[kt][e] *= inv;
    }

#pragma unroll
    for (int kt = 0; kt < 13; ++kt) {
#pragma unroll
      for (int e = 0; e < 4; ++e)
        Ps[wave][hi * 4 + e][kt * 16 + lo] = __float2bfloat16(s[kt][e]);
    }

    f32x4 o[2] = {{0.f, 0.f, 0.f, 0.f}, {0.f, 0.f, 0.f, 0.f}};
#pragma unroll
    for (int c = 0; c < 7; ++c) {
      short8 pa = *(const short8*)(&Ps[wave][lo][c * 32 + hi * 8]);
#pragma unroll
      for (int n = 0; n < 2; ++n) {
        short8 vf = *(const short8*)(&Vt[n * 16 + lo][c * 32 + hi * 8]);
        o[n] = __builtin_amdgcn_mfma_f32_16x16x32_bf16(pa, vf, o[n], 0, 0, 0);
      }
    }

#pragma unroll
    for (int n = 0; n < 2; ++n) {
#pragma unroll
      for (int e = 0; e < 4; ++e) {
        int qg = qt * 16 + hi * 4 + e;
        if (qg < NTOK)
          out[(size_t)(b * NTOK + qg) * NDIM + h * HD + n * 16 + lo] = __float2bfloat16(o[n][e]);
      }
    }
  }
}

extern "C" void kernel_launch(void* const* d_in, const int* in_sizes, int n_in,
                              void* d_out, int out_size, void* d_ws, size_t ws_size,
                              hipStream_t stream) {
  const float* x       = (const float*)d_in[0];
  const float* norm1_w = (const float*)d_in[1];
  const float* norm1_b = (const float*)d_in[2];
  const float* qkv_w   = (const float*)d_in[3];
  const float* qkv_b   = (const float*)d_in[4];
  const float* proj_w  = (const float*)d_in[5];
  const float* proj_b  = (const float*)d_in[6];
  const float* rpb     = (const float*)d_in[7];
  const float* norm2_w = (const float*)d_in[8];
  const float* norm2_b = (const float*)d_in[9];
  const float* fc1_w   = (const float*)d_in[10];
  const float* fc1_b   = (const float*)d_in[11];
  const float* fc2_w   = (const float*)d_in[12];
  const float* fc2_b   = (const float*)d_in[13];
  const int*   rpi     = (const int*)d_in[14];
  float* out = (float*)d_out;

  char* ws = (char*)d_ws;
  bf16* qkv_buf = (bf16*)ws;              // region 0: qkv bf16, later mlp1 bf16
  bf16* mlp1 = (bf16*)ws;
  bf16* hbuf = (bf16*)(ws + 154140672);   // region 1: h1 -> attn_out -> h2
  bf16* wqkv_t = (bf16*)(ws + 154140672 + 38535168);
  bf16* wproj_t = wqkv_t + 442368;
  bf16* wfc1_t = wproj_t + 147456;
  bf16* wfc2_t = wfc1_t + 589824;
  float* bias_mat = (float*)(wfc2_t + 589824);  // 12*196*196 f32

  k_transpose_bf16<<<(442368 + 255) / 256, 256, 0, stream>>>(qkv_w, wqkv_t, 384, 1152);
  k_transpose_bf16<<<(147456 + 255) / 256, 256, 0, stream>>>(proj_w, wproj_t, 384, 384);
  k_transpose_bf16<<<(589824 + 255) / 256, 256, 0, stream>>>(fc1_w, wfc1_t, 384, 1536);
  k_transpose_bf16<<<(589824 + 255) / 256, 256, 0, stream>>>(fc2_w, wfc2_t, 1536, 384);
  k_build_bias<<<(NTOK * NTOK + 255) / 256, 256, 0, stream>>>(rpb, rpi, bias_mat);

  // h1 = LN1(x)
  k_layernorm<<<M_TOK / 4, 256, 0, stream>>>(x, norm1_w, norm1_b, hbuf);
  // qkv = h1 @ qkv_w + qkv_b   (grid 9*392 = 3528, %8==0)
  k_gemm_bt<0><<<9 * 392, 256, 0, stream>>>(hbuf, wqkv_t, qkv_b, nullptr, qkv_buf, 1152, 384, 9);
  // attn_out = softmax(q k^T * scale + bias) v
  k_attn<<<dim3(NHEADS, NBATCH), 256, 0, stream>>>(qkv_buf, bias_mat, hbuf);
  // x2 = x + attn_out @ proj_w + proj_b   (grid 3*392 = 1176, %8==0)
  k_gemm_bt<2><<<3 * 392, 256, 0, stream>>>(hbuf, wproj_t, proj_b, x, out, 384, 384, 3);
  // h2 = LN2(x2)
  k_layernorm<<<M_TOK / 4, 256, 0, stream>>>(out, norm2_w, norm2_b, hbuf);
  // mlp1 = gelu(h2 @ fc1_w + fc1_b)   (grid 12*392 = 4704, %8==0)
  k_gemm_bt<1><<<12 * 392, 256, 0, stream>>>(hbuf, wfc1_t, fc1_b, nullptr, mlp1, 1536, 384, 12);
  // out = x2 + mlp1 @ fc2_w + fc2_b   (grid 3*392 = 1176, %8==0)
  k_gemm_bt<2><<<3 * 392, 256, 0, stream>>>(mlp1, wfc2_t, fc2_b, out, out, 384, 1536, 3);
}